// Round 1
// baseline (812.593 us; speedup 1.0000x reference)
//
#include <hip/hip_runtime.h>
#include <math.h>

#define BD 4
#define CD 64
#define HD 128
#define WD 128
#define FD 5
#define LD 512
#define NHD 128
#define HW (HD*WD)

// workspace layout (float offsets)
#define OFF_MU      0                     // [B][F][L]          10240
#define OFF_TG      10240                 // [B][6][9][64]      13824
#define OFF_TB      24064                 // [B][6][9][64]      13824
#define OFF_MEAN    37888                 // [256]
#define OFF_RSTD    38144                 // [256]
#define OFF_WG2     38400                 // [9][128][64]       73728
#define OFF_WB2     112128                // [9][128][64]       73728
#define OFF_ACTV    185856                // [B][H][W][NH]      8388608
#define OFF_IDX_BYTES ((size_t)(185856 + 8388608) * 4)   // u8 [B][H][W] 65536

// ---------------- kernel 1: mu[b,f,k] = relu(fc_w[f,k,:]·codes[b,f,:] + fc_b[f,k])
__global__ void k_style(const float* __restrict__ codes, const float* __restrict__ fc_w,
                        const float* __restrict__ fc_b, float* __restrict__ mu) {
    int bf = blockIdx.x;            // b*5+f, 20 blocks
    int f = bf % 5;
    __shared__ float cs[LD];
    int t = threadIdx.x;            // 512 threads
    cs[t] = codes[(size_t)bf * LD + t];
    __syncthreads();
    const float* wrow = fc_w + ((size_t)(f * LD + t)) * LD;
    float acc = 0.f;
    for (int l = 0; l < LD; l += 4) {
        float4 wv = *(const float4*)(wrow + l);
        float4 cv = *(const float4*)(cs + l);
        acc += wv.x * cv.x + wv.y * cv.y + wv.z * cv.z + wv.w * cv.w;
    }
    acc += fc_b[f * LD + t];
    mu[(size_t)bf * LD + t] = fmaxf(acc, 0.f);
}

// ---------------- kernel 2: T[b][f][tap][o] = sum_c mu[b,f,c] * convw[o,c,tap]; f==5 -> 0
__global__ void k_ttab(const float* __restrict__ mu, const float* __restrict__ wg,
                       const float* __restrict__ wb, float* __restrict__ Tg,
                       float* __restrict__ Tb) {
    int bf = blockIdx.x;            // b*6+f, 24 blocks
    int b = bf / 6, f = bf % 6;
    float* tg = Tg + (size_t)bf * 576;
    float* tb = Tb + (size_t)bf * 576;
    int t = threadIdx.x;            // 256
    if (f == 5) {
        for (int e = t; e < 576; e += 256) { tg[e] = 0.f; tb[e] = 0.f; }
        return;
    }
    __shared__ float ms[LD];
    for (int i = t; i < LD; i += 256) ms[i] = mu[((size_t)b * 5 + f) * LD + i];
    __syncthreads();
    for (int e = t; e < 576; e += 256) {
        int k = e >> 6, o = e & 63;
        const float* wp = wg + (size_t)o * LD * 9 + k;
        const float* wq = wb + (size_t)o * LD * 9 + k;
        float ag = 0.f, ab = 0.f;
        for (int c = 0; c < LD; ++c) {
            float m = ms[c];
            ag = fmaf(m, wp[(size_t)c * 9], ag);
            ab = fmaf(m, wq[(size_t)c * 9], ab);
        }
        tg[e] = ag; tb[e] = ab;
    }
}

// ---------------- kernel 2b: rearrange spade weights [o][n][tap] -> [tap][n][o]
__global__ void k_wre(const float* __restrict__ wg, const float* __restrict__ wb,
                      float* __restrict__ Wg2, float* __restrict__ Wb2) {
    int e = blockIdx.x * 256 + threadIdx.x;       // 9*128*64 = 73728
    if (e >= 73728) return;
    int o = e & 63, n = (e >> 6) & 127, k = e >> 13;
    Wg2[e] = wg[((size_t)o * 128 + n) * 9 + k];
    Wb2[e] = wb[((size_t)o * 128 + n) * 9 + k];
}

// ---------------- kernel 3: region index map (last f with segmap>0, else 5)
__global__ void k_idx(const float* __restrict__ segmap, unsigned char* __restrict__ idx) {
    int pid = blockIdx.x * 256 + threadIdx.x;     // 65536
    int b = pid >> 14, p = pid & 16383;
    unsigned char v = 5;
    for (int f = 0; f < 5; ++f)
        if (segmap[((size_t)b * 5 + f) * HW + p] > 0.f) v = (unsigned char)f;
    idx[pid] = v;
}

// ---------------- kernel 4: instance-norm stats per (b,c) plane
__global__ void k_stats(const float* __restrict__ x, float* __restrict__ meanp,
                        float* __restrict__ rstdp) {
    int plane = blockIdx.x;         // 256
    const float* xp = x + (size_t)plane * HW;
    int t = threadIdx.x;            // 256
    float s = 0.f, s2 = 0.f;
    for (int j = 0; j < 16; ++j) {
        float4 v = *(const float4*)(xp + ((size_t)t + j * 256) * 4);
        s += v.x + v.y + v.z + v.w;
        s2 += v.x * v.x + v.y * v.y + v.z * v.z + v.w * v.w;
    }
    for (int off = 32; off; off >>= 1) { s += __shfl_xor(s, off); s2 += __shfl_xor(s2, off); }
    __shared__ float as[4], as2[4];
    int wid = t >> 6;
    if ((t & 63) == 0) { as[wid] = s; as2[wid] = s2; }
    __syncthreads();
    if (t == 0) {
        s = as[0] + as[1] + as[2] + as[3];
        s2 = as2[0] + as2[1] + as2[2] + as2[3];
        float m = s * (1.f / HW);
        float var = s2 * (1.f / HW) - m * m;
        meanp[plane] = m;
        rstdp[plane] = rsqrtf(var + 1e-5f);
    }
}

// ---------------- kernel 5: actv = relu(conv2d(mask, shared_w) + b), stored NHWC
__global__ void k_shared(const float* __restrict__ mask, const float* __restrict__ w,
                         const float* __restrict__ bias, float* __restrict__ actv) {
    __shared__ float ml[3][3][66];        // [c][ky][col]
    __shared__ float wl[NHD * 27];
    __shared__ float bl[NHD];
    int t = threadIdx.x;                  // 256
    int w0 = blockIdx.x * 64, h = blockIdx.y, b = blockIdx.z;
    for (int e = t; e < NHD * 27; e += 256) wl[e] = w[e];
    if (t < NHD) bl[t] = bias[t];
    for (int e = t; e < 594; e += 256) {
        int col = e % 66; int rc = e / 66; int ky = rc % 3; int c = rc / 3;
        int y = h - 1 + ky; int xx = w0 - 1 + col;
        float v = 0.f;
        if ((unsigned)y < 128u && (unsigned)xx < 128u)
            v = mask[(((size_t)b * 3 + c) * HD + y) * WD + xx];
        ml[c][ky][col] = v;
    }
    __syncthreads();
    int n = t & 127, wh = t >> 7;
    const float* wn = wl + n * 27;
    float* outp = actv + ((((size_t)b * HD + h) * WD) + w0 + wh * 32) * NHD + n;
    for (int i = 0; i < 32; ++i) {
        int pcol = wh * 32 + i;
        float acc = bl[n];
        #pragma unroll
        for (int c = 0; c < 3; ++c)
            #pragma unroll
            for (int ky = 0; ky < 3; ++ky)
                #pragma unroll
                for (int kx = 0; kx < 3; ++kx)
                    acc = fmaf(ml[c][ky][pcol + kx], wn[(c * 3 + ky) * 3 + kx], acc);
        outp[(size_t)i * NHD] = fmaxf(acc, 0.f);
    }
}

// ---------------- kernel 6: fused spade-GEMM + avg-lookup + instance-norm + blend
__global__ void __launch_bounds__(256)
k_main(const float* __restrict__ x, const float* __restrict__ actv,
       const unsigned char* __restrict__ idxm,
       const float* __restrict__ Tg, const float* __restrict__ Tb,
       const float* __restrict__ Wg2, const float* __restrict__ Wb2,
       const float* __restrict__ meanp, const float* __restrict__ rstdp,
       const float* __restrict__ cgb, const float* __restrict__ cbb,
       const float* __restrict__ sgb, const float* __restrict__ sbb,
       const float* __restrict__ bgam, const float* __restrict__ bbet,
       float* __restrict__ out) {
    __shared__ float Ag[32 * 68], Ab[32 * 68], Bt[32 * 68];
    __shared__ unsigned char ir[3][66];
    int t = threadIdx.x;
    int w0 = blockIdx.x * 64, h = blockIdx.y, b = blockIdx.z;

    for (int e = t; e < 198; e += 256) {
        int r = e / 66, j = e % 66;
        int y = h - 1 + r, xx = w0 + j - 1;
        ir[r][j] = ((unsigned)y < 128u && (unsigned)xx < 128u)
                       ? idxm[((size_t)b << 14) + (y << 7) + xx] : (unsigned char)5;
    }

    float accg[16], accb[16];
    #pragma unroll
    for (int i = 0; i < 16; ++i) { accg[i] = 0.f; accb[i] = 0.f; }
    int p4 = t & 15, oq = t >> 4;
    int pS = t >> 2, nqS = t & 3;

    for (int tap = 0; tap < 9; ++tap) {
        int ky = tap / 3, kx = tap % 3;
        int y = h - 1 + ky;
        int xs = w0 + pS + kx - 1;
        bool bok = ((unsigned)y < 128u) && ((unsigned)xs < 128u);
        const float* arow = actv + (((long long)(b * HD + y) * WD) + xs) * NHD;
        for (int nc = 0; nc < 128; nc += 32) {
            __syncthreads();
            #pragma unroll
            for (int i = 0; i < 2; ++i) {               // stage A (weights)
                int q = t * 2 + i;
                int n = q >> 4, o = (q & 15) * 4;
                float4 g = *(const float4*)(Wg2 + ((size_t)tap * 128 + nc + n) * 64 + o);
                float4 v = *(const float4*)(Wb2 + ((size_t)tap * 128 + nc + n) * 64 + o);
                *(float4*)(Ag + n * 68 + o) = g;
                *(float4*)(Ab + n * 68 + o) = v;
            }
            #pragma unroll
            for (int i = 0; i < 2; ++i) {               // stage B (actv patch, transpose)
                int n8 = nqS * 8 + i * 4;
                float4 v = make_float4(0.f, 0.f, 0.f, 0.f);
                if (bok) v = *(const float4*)(arow + nc + n8);
                Bt[(n8 + 0) * 68 + pS] = v.x;
                Bt[(n8 + 1) * 68 + pS] = v.y;
                Bt[(n8 + 2) * 68 + pS] = v.z;
                Bt[(n8 + 3) * 68 + pS] = v.w;
            }
            __syncthreads();
            #pragma unroll
            for (int n = 0; n < 32; ++n) {
                float4 bv = *(const float4*)(Bt + n * 68 + p4 * 4);
                float4 gv = *(const float4*)(Ag + n * 68 + oq * 4);
                float4 av = *(const float4*)(Ab + n * 68 + oq * 4);
                float bb4[4] = {bv.x, bv.y, bv.z, bv.w};
                float gg4[4] = {gv.x, gv.y, gv.z, gv.w};
                float aa4[4] = {av.x, av.y, av.z, av.w};
                #pragma unroll
                for (int i = 0; i < 4; ++i)
                    #pragma unroll
                    for (int j = 0; j < 4; ++j) {
                        accg[i * 4 + j] = fmaf(bb4[i], gg4[j], accg[i * 4 + j]);
                        accb[i * 4 + j] = fmaf(bb4[i], aa4[j], accb[i * 4 + j]);
                    }
            }
        }
    }

    // ---- epilogue
    float ga = 1.f / (1.f + __expf(-bgam[0]));
    float ba = 1.f / (1.f + __expf(-bbet[0]));
    int ob = oq * 4;
    float4 t4;
    t4 = *(const float4*)(cgb + ob); float cg_a[4] = {t4.x, t4.y, t4.z, t4.w};
    t4 = *(const float4*)(cbb + ob); float cb_a[4] = {t4.x, t4.y, t4.z, t4.w};
    t4 = *(const float4*)(sgb + ob); float sg_a[4] = {t4.x, t4.y, t4.z, t4.w};
    t4 = *(const float4*)(sbb + ob); float sb_a[4] = {t4.x, t4.y, t4.z, t4.w};

    float avg_g[4][4], avg_b[4][4];          // [pix][o]
    #pragma unroll
    for (int i = 0; i < 4; ++i) {
        int p = p4 * 4 + i;
        float ag[4] = {cg_a[0], cg_a[1], cg_a[2], cg_a[3]};
        float ab2[4] = {cb_a[0], cb_a[1], cb_a[2], cb_a[3]};
        #pragma unroll
        for (int ky = 0; ky < 3; ++ky)
            #pragma unroll
            for (int kx = 0; kx < 3; ++kx) {
                int f = ir[ky][p + kx];
                size_t base = (((size_t)b * 6 + f) * 9 + ky * 3 + kx) * 64 + ob;
                float4 tg4 = *(const float4*)(Tg + base);
                float4 tb4 = *(const float4*)(Tb + base);
                ag[0] += tg4.x; ag[1] += tg4.y; ag[2] += tg4.z; ag[3] += tg4.w;
                ab2[0] += tb4.x; ab2[1] += tb4.y; ab2[2] += tb4.z; ab2[3] += tb4.w;
            }
        #pragma unroll
        for (int j = 0; j < 4; ++j) { avg_g[i][j] = ag[j]; avg_b[i][j] = ab2[j]; }
    }

    #pragma unroll
    for (int j = 0; j < 4; ++j) {
        int plane = b * 64 + ob + j;
        float m = meanp[plane], r = rstdp[plane];
        size_t rowoff = ((size_t)plane * HD + h) * WD + w0 + p4 * 4;
        float4 xv = *(const float4*)(x + rowoff);
        float xa[4] = {xv.x, xv.y, xv.z, xv.w};
        float res[4];
        #pragma unroll
        for (int i = 0; i < 4; ++i) {
            float gs = accg[i * 4 + j] + sg_a[j];
            float bs = accb[i * 4 + j] + sb_a[j];
            float gf = ga * avg_g[i][j] + (1.f - ga) * gs;
            float bf = ba * avg_b[i][j] + (1.f - ba) * bs;
            float xn = (xa[i] - m) * r;
            res[i] = xn * (1.f + gf) + bf;
        }
        *(float4*)(out + rowoff) = make_float4(res[0], res[1], res[2], res[3]);
    }
}

extern "C" void kernel_launch(void* const* d_in, const int* in_sizes, int n_in,
                              void* d_out, int out_size, void* d_ws, size_t ws_size,
                              hipStream_t stream) {
    const float* x      = (const float*)d_in[0];
    const float* segmap = (const float*)d_in[1];
    const float* codes  = (const float*)d_in[2];
    const float* mask   = (const float*)d_in[3];
    const float* fc_w   = (const float*)d_in[4];
    const float* fc_b   = (const float*)d_in[5];
    const float* cgw    = (const float*)d_in[6];
    const float* cgb    = (const float*)d_in[7];
    const float* cbw    = (const float*)d_in[8];
    const float* cbb    = (const float*)d_in[9];
    const float* ssw    = (const float*)d_in[10];
    const float* ssb    = (const float*)d_in[11];
    const float* sgw    = (const float*)d_in[12];
    const float* sgb    = (const float*)d_in[13];
    const float* sbw    = (const float*)d_in[14];
    const float* sbb    = (const float*)d_in[15];
    const float* bgam   = (const float*)d_in[16];
    const float* bbet   = (const float*)d_in[17];
    float* out = (float*)d_out;

    float* wsf = (float*)d_ws;
    float* mu    = wsf + OFF_MU;
    float* Tg    = wsf + OFF_TG;
    float* Tb    = wsf + OFF_TB;
    float* meanp = wsf + OFF_MEAN;
    float* rstdp = wsf + OFF_RSTD;
    float* Wg2   = wsf + OFF_WG2;
    float* Wb2   = wsf + OFF_WB2;
    float* actv  = wsf + OFF_ACTV;
    unsigned char* idxm = (unsigned char*)d_ws + OFF_IDX_BYTES;

    k_style<<<20, 512, 0, stream>>>(codes, fc_w, fc_b, mu);
    k_ttab<<<24, 256, 0, stream>>>(mu, cgw, cbw, Tg, Tb);
    k_wre<<<288, 256, 0, stream>>>(sgw, sbw, Wg2, Wb2);
    k_idx<<<256, 256, 0, stream>>>(segmap, idxm);
    k_stats<<<256, 256, 0, stream>>>(x, meanp, rstdp);
    k_shared<<<dim3(2, 128, 4), 256, 0, stream>>>(mask, ssw, ssb, actv);
    k_main<<<dim3(2, 128, 4), 256, 0, stream>>>(x, actv, idxm, Tg, Tb, Wg2, Wb2,
                                                meanp, rstdp, cgb, cbb, sgb, sbb,
                                                bgam, bbet, out);
}

// Round 2
// 223.618 us; speedup vs baseline: 3.6338x; 3.6338x over previous
//
#include <hip/hip_runtime.h>
#include <math.h>

#define BD 4
#define CD 64
#define HD 128
#define WD 128
#define FD 5
#define LD 512
#define NHD 128
#define HW (HD*WD)

typedef _Float16 half8 __attribute__((ext_vector_type(8)));
typedef float floatx4 __attribute__((ext_vector_type(4)));

// ---------------- workspace layout (float offsets) ----------------
#define OFF_MU      0                      // [B][F][L]              10240
#define OFF_TG      10240                  // [B][6][9][64]          13824
#define OFF_TB      24064                  // [B][6][9][64]          13824
#define OFF_MEAN    37888                  // [256]
#define OFF_RSTD    38144                  // [256]
#define OFF_CT      38400                  // fp32 [2][9][512][64]   589824
#define OFF_W2H     628224                 // f16  [2][9][64][128]   147456 halves = 73728 floats
#define OFF_ACTVH   701952                 // f16  [B][H][W][NH]     8388608 halves = 4194304 floats
#define OFF_IDX_BYTES ((size_t)(701952 + 4194304) * 4)   // u8 [B][H][W] 65536 bytes

// ---------------- k_style: mu[b,f,k] = relu(fc_w[f,k,:]·codes[b,f,:] + fc_b[f,k])
// 8-lane cooperative rows -> coalesced 128B segments
__global__ void k_style(const float* __restrict__ codes, const float* __restrict__ fc_w,
                        const float* __restrict__ fc_b, float* __restrict__ mu) {
    int bf = blockIdx.x;            // b*5+f, 20 blocks
    int f = bf % 5;
    __shared__ float cs[LD];
    int t = threadIdx.x;            // 512 threads
    cs[t] = codes[(size_t)bf * LD + t];
    __syncthreads();
    for (int pass = 0; pass < 8; ++pass) {
        int k = pass * 64 + (t >> 3);
        const float* wrow = fc_w + ((size_t)f * LD + k) * LD;
        float acc = 0.f;
        for (int j = 0; j < 16; ++j) {
            int l = (t & 7) * 4 + j * 32;
            float4 wv = *(const float4*)(wrow + l);
            float4 cv = *(const float4*)(cs + l);
            acc += wv.x * cv.x + wv.y * cv.y + wv.z * cv.z + wv.w * cv.w;
        }
        acc += __shfl_xor(acc, 1);
        acc += __shfl_xor(acc, 2);
        acc += __shfl_xor(acc, 4);
        if ((t & 7) == 0)
            mu[(size_t)bf * LD + k] = fmaxf(acc + fc_b[f * LD + k], 0.f);
    }
}

// ---------------- k_prep: weight transposes
//  CT  (fp32): cgw/cbw [64][512][9] -> [2][9][512][64]   (for k_ttab, coalesced)
//  W2h (f16) : sgw/sbw [64][128][9] -> [2][9][64][128]   (B^T fragments for k_main)
__global__ void k_prep(const float* __restrict__ cgw, const float* __restrict__ cbw,
                       const float* __restrict__ sgw, const float* __restrict__ sbw,
                       float* __restrict__ CT, _Float16* __restrict__ W2h) {
    int e = blockIdx.x * 256 + threadIdx.x;
    if (e < 589824) {
        int tbl = e / 294912; int r = e % 294912;
        int tap = r >> 15;            // / (512*64)
        int c = (r >> 6) & 511;
        int o = r & 63;
        const float* src = tbl ? cbw : cgw;
        CT[e] = src[((size_t)o * 512 + c) * 9 + tap];
    } else if (e < 589824 + 147456) {
        int r = e - 589824;
        int q = r % 73728; int tbl = r / 73728;
        int tap = q >> 13;            // / (64*128)
        int oc = (q >> 7) & 63;
        int c = q & 127;
        const float* src = tbl ? sbw : sgw;
        W2h[r] = (_Float16)src[((size_t)oc * 128 + c) * 9 + tap];
    }
}

// ---------------- k_ttab: T[b][f][tap][o] = sum_c mu[b,f,c]*convw[o,c,tap]; f==5 -> 0
__global__ void k_ttab(const float* __restrict__ mu, const float* __restrict__ CT,
                       float* __restrict__ Tg, float* __restrict__ Tb) {
    int bid = blockIdx.x;            // ((b*6+f)*9+tap), 216 blocks
    int tap = bid % 9; int bf6 = bid / 9;
    int f = bf6 % 6, b = bf6 / 6;
    int t = threadIdx.x;             // 256
    size_t base = (size_t)bid * 64;
    if (f == 5) {
        if (t < 64) { Tg[base + t] = 0.f; Tb[base + t] = 0.f; }
        return;
    }
    __shared__ float ms[LD];
    __shared__ float red[2][4][64];
    for (int i = t; i < LD; i += 256) ms[i] = mu[((size_t)b * 5 + f) * LD + i];
    __syncthreads();
    int o = t & 63, cq = t >> 6;
    const float* cg = CT + ((size_t)tap * 512 + cq * 128) * 64 + o;
    const float* cb = cg + 294912;
    float ag = 0.f, ab = 0.f;
    #pragma unroll 4
    for (int i = 0; i < 128; ++i) {
        float m = ms[cq * 128 + i];
        ag = fmaf(m, cg[(size_t)i * 64], ag);
        ab = fmaf(m, cb[(size_t)i * 64], ab);
    }
    red[0][cq][o] = ag; red[1][cq][o] = ab;
    __syncthreads();
    if (t < 128) {
        int tb2 = t >> 6, oo = t & 63;
        float s = red[tb2][0][oo] + red[tb2][1][oo] + red[tb2][2][oo] + red[tb2][3][oo];
        if (tb2 == 0) Tg[base + oo] = s; else Tb[base + oo] = s;
    }
}

// ---------------- k_idx: region index map (last f with segmap>0, else 5)
__global__ void k_idx(const float* __restrict__ segmap, unsigned char* __restrict__ idx) {
    int pid = blockIdx.x * 256 + threadIdx.x;     // 65536
    int b = pid >> 14, p = pid & 16383;
    unsigned char v = 5;
    for (int f = 0; f < 5; ++f)
        if (segmap[((size_t)b * 5 + f) * HW + p] > 0.f) v = (unsigned char)f;
    idx[pid] = v;
}

// ---------------- k_stats: instance-norm stats per (b,c) plane
__global__ void k_stats(const float* __restrict__ x, float* __restrict__ meanp,
                        float* __restrict__ rstdp) {
    int plane = blockIdx.x;         // 256
    const float* xp = x + (size_t)plane * HW;
    int t = threadIdx.x;            // 256
    float s = 0.f, s2 = 0.f;
    for (int j = 0; j < 16; ++j) {
        float4 v = *(const float4*)(xp + ((size_t)t + j * 256) * 4);
        s += v.x + v.y + v.z + v.w;
        s2 += v.x * v.x + v.y * v.y + v.z * v.z + v.w * v.w;
    }
    for (int off = 32; off; off >>= 1) { s += __shfl_xor(s, off); s2 += __shfl_xor(s2, off); }
    __shared__ float as[4], as2[4];
    int wid = t >> 6;
    if ((t & 63) == 0) { as[wid] = s; as2[wid] = s2; }
    __syncthreads();
    if (t == 0) {
        s = as[0] + as[1] + as[2] + as[3];
        s2 = as2[0] + as2[1] + as2[2] + as2[3];
        float m = s * (1.f / HW);
        float var = s2 * (1.f / HW) - m * m;
        meanp[plane] = m;
        rstdp[plane] = rsqrtf(var + 1e-5f);
    }
}

// ---------------- k_shared: actv = relu(conv2d(mask, shared_w)+b), stored NHWC f16
__global__ void k_shared(const float* __restrict__ mask, const float* __restrict__ w,
                         const float* __restrict__ bias, _Float16* __restrict__ actvh) {
    __shared__ float ml[3][3][66];        // [c][ky][col]
    __shared__ float wl[NHD * 27];
    __shared__ float bl[NHD];
    int t = threadIdx.x;                  // 256
    int w0 = blockIdx.x * 64, h = blockIdx.y, b = blockIdx.z;
    for (int e = t; e < NHD * 27; e += 256) wl[e] = w[e];
    if (t < NHD) bl[t] = bias[t];
    for (int e = t; e < 594; e += 256) {
        int col = e % 66; int rc = e / 66; int ky = rc % 3; int c = rc / 3;
        int y = h - 1 + ky; int xx = w0 - 1 + col;
        float v = 0.f;
        if ((unsigned)y < 128u && (unsigned)xx < 128u)
            v = mask[(((size_t)b * 3 + c) * HD + y) * WD + xx];
        ml[c][ky][col] = v;
    }
    __syncthreads();
    int n = t & 127, wh = t >> 7;
    const float* wn = wl + n * 27;
    _Float16* outp = actvh + ((((size_t)b * HD + h) * WD) + w0 + wh * 32) * NHD + n;
    for (int i = 0; i < 32; ++i) {
        int pcol = wh * 32 + i;
        float acc = bl[n];
        #pragma unroll
        for (int c = 0; c < 3; ++c)
            #pragma unroll
            for (int ky = 0; ky < 3; ++ky)
                #pragma unroll
                for (int kx = 0; kx < 3; ++kx)
                    acc = fmaf(ml[c][ky][pcol + kx], wn[(c * 3 + ky) * 3 + kx], acc);
        outp[(size_t)i * NHD] = (_Float16)fmaxf(acc, 0.f);
    }
}

// ---------------- k_main: MFMA f16 SPADE-GEMM + avg table lookup + IN + blend
// block = 64 pixels (one row-strip) x 64 oc; 4 waves, wave w owns oc 16w..16w+15.
// A (pixels x K) staged in LDS once (XOR ch-group swizzle); B frags straight from L2.
__global__ void __launch_bounds__(256)
k_main(const float* __restrict__ x, const _Float16* __restrict__ actvh,
       const unsigned char* __restrict__ idxm,
       const float* __restrict__ Tg, const float* __restrict__ Tb,
       const _Float16* __restrict__ W2h,
       const float* __restrict__ meanp, const float* __restrict__ rstdp,
       const float* __restrict__ cgb, const float* __restrict__ cbb,
       const float* __restrict__ sgb, const float* __restrict__ sbb,
       const float* __restrict__ bgam, const float* __restrict__ bbet,
       float* __restrict__ out) {
    __shared__ _Float16 As[3 * 66 * 128];     // 50688 B
    __shared__ unsigned char ir[3][66];
    int t = threadIdx.x;
    int w0 = blockIdx.x * 64, h = blockIdx.y, b = blockIdx.z;

    // stage 3 actv rows x 66 cols x 128 ch (f16), ch-group XOR-swizzled by col
    for (int e = t; e < 3168; e += 256) {
        int ch8 = e & 15;
        int col = (e >> 4) % 66;
        int row = e / 1056;
        int y = h - 1 + row, xx = w0 - 1 + col;
        uint4 v = make_uint4(0u, 0u, 0u, 0u);
        if ((unsigned)y < 128u && (unsigned)xx < 128u)
            v = *(const uint4*)(actvh + ((((size_t)b * HD + y) * WD + xx) << 7) + ch8 * 8);
        int g8 = ch8 ^ (col & 7);
        *(uint4*)(&As[(size_t)(row * 66 + col) * 128 + g8 * 8]) = v;
    }
    for (int e = t; e < 198; e += 256) {
        int r = e / 66, j = e % 66;
        int y = h - 1 + r, xx = w0 + j - 1;
        ir[r][j] = ((unsigned)y < 128u && (unsigned)xx < 128u)
                       ? idxm[((size_t)b << 14) + (y << 7) + xx] : (unsigned char)5;
    }
    __syncthreads();

    int lane = t & 63, w = t >> 6;
    int l15 = lane & 15, lg = lane >> 4;
    int ocl = w * 16 + l15;

    floatx4 zero4 = {0.f, 0.f, 0.f, 0.f};
    floatx4 accg[4], accb[4];
    #pragma unroll
    for (int m = 0; m < 4; ++m) { accg[m] = zero4; accb[m] = zero4; }

    const _Float16* Wg = W2h;
    const _Float16* Wb = W2h + 73728;

    for (int tap = 0; tap < 9; ++tap) {
        int ky = tap / 3, kx = tap % 3;
        const _Float16* wgt = Wg + ((size_t)tap * 64 + ocl) * 128 + lg * 8;
        const _Float16* wbt = Wb + ((size_t)tap * 64 + ocl) * 128 + lg * 8;
        int cx7 = (l15 + kx) & 7;
        int rowbase = ky * 66 * 128;
        #pragma unroll
        for (int cb = 0; cb < 4; ++cb) {
            half8 bg = *(const half8*)(wgt + cb * 32);
            half8 bb = *(const half8*)(wbt + cb * 32);
            int swz = ((cb * 4 + lg) ^ cx7) * 8;
            #pragma unroll
            for (int m = 0; m < 4; ++m) {
                int c = m * 16 + l15 + kx;
                half8 a = *(const half8*)(&As[rowbase + c * 128 + swz]);
                accg[m] = __builtin_amdgcn_mfma_f32_16x16x32_f16(a, bg, accg[m], 0, 0, 0);
                accb[m] = __builtin_amdgcn_mfma_f32_16x16x32_f16(a, bb, accb[m], 0, 0, 0);
            }
        }
    }

    // ---- epilogue: per lane one oc, 16 pixels
    float ga = 1.f / (1.f + __expf(-bgam[0]));
    float ba = 1.f / (1.f + __expf(-bbet[0]));
    float sg = sgb[ocl], sb = sbb[ocl];
    float cg = cgb[ocl], cb2 = cbb[ocl];
    int plane = b * 64 + ocl;
    float mean = meanp[plane], rstd = rstdp[plane];
    const float* xrow = x + ((size_t)plane * HD + h) * WD + w0;
    float* orow = out + ((size_t)plane * HD + h) * WD + w0;

    #pragma unroll
    for (int m = 0; m < 4; ++m) {
        int p0 = m * 16 + lg * 4;
        float4 xv = *(const float4*)(xrow + p0);
        float xa[4] = {xv.x, xv.y, xv.z, xv.w};
        float res[4];
        #pragma unroll
        for (int r = 0; r < 4; ++r) {
            int p = p0 + r;
            float ag = cg, ab = cb2;
            #pragma unroll
            for (int ky2 = 0; ky2 < 3; ++ky2)
                #pragma unroll
                for (int kx2 = 0; kx2 < 3; ++kx2) {
                    int f = ir[ky2][p + kx2];
                    size_t tbase = ((size_t)(b * 6 + f) * 9 + ky2 * 3 + kx2) * 64 + ocl;
                    ag += Tg[tbase];
                    ab += Tb[tbase];
                }
            float gs = accg[m][r] + sg;
            float bs = accb[m][r] + sb;
            float gf = ga * ag + (1.f - ga) * gs;
            float bf = ba * ab + (1.f - ba) * bs;
            res[r] = (xa[r] - mean) * rstd * (1.f + gf) + bf;
        }
        *(float4*)(orow + p0) = make_float4(res[0], res[1], res[2], res[3]);
    }
}

extern "C" void kernel_launch(void* const* d_in, const int* in_sizes, int n_in,
                              void* d_out, int out_size, void* d_ws, size_t ws_size,
                              hipStream_t stream) {
    const float* x      = (const float*)d_in[0];
    const float* segmap = (const float*)d_in[1];
    const float* codes  = (const float*)d_in[2];
    const float* mask   = (const float*)d_in[3];
    const float* fc_w   = (const float*)d_in[4];
    const float* fc_b   = (const float*)d_in[5];
    const float* cgw    = (const float*)d_in[6];
    const float* cgb    = (const float*)d_in[7];
    const float* cbw    = (const float*)d_in[8];
    const float* cbb    = (const float*)d_in[9];
    const float* ssw    = (const float*)d_in[10];
    const float* ssb    = (const float*)d_in[11];
    const float* sgw    = (const float*)d_in[12];
    const float* sgb    = (const float*)d_in[13];
    const float* sbw    = (const float*)d_in[14];
    const float* sbb    = (const float*)d_in[15];
    const float* bgam   = (const float*)d_in[16];
    const float* bbet   = (const float*)d_in[17];
    float* out = (float*)d_out;

    float* wsf = (float*)d_ws;
    float* mu    = wsf + OFF_MU;
    float* Tg    = wsf + OFF_TG;
    float* Tb    = wsf + OFF_TB;
    float* meanp = wsf + OFF_MEAN;
    float* rstdp = wsf + OFF_RSTD;
    float* CT    = wsf + OFF_CT;
    _Float16* W2h   = (_Float16*)(wsf + OFF_W2H);
    _Float16* actvh = (_Float16*)(wsf + OFF_ACTVH);
    unsigned char* idxm = (unsigned char*)d_ws + OFF_IDX_BYTES;

    k_style<<<20, 512, 0, stream>>>(codes, fc_w, fc_b, mu);
    k_prep<<<2880, 256, 0, stream>>>(cgw, cbw, sgw, sbw, CT, W2h);
    k_ttab<<<216, 256, 0, stream>>>(mu, CT, Tg, Tb);
    k_idx<<<256, 256, 0, stream>>>(segmap, idxm);
    k_stats<<<256, 256, 0, stream>>>(x, meanp, rstdp);
    k_shared<<<dim3(2, 128, 4), 256, 0, stream>>>(mask, ssw, ssb, actvh);
    k_main<<<dim3(2, 128, 4), 256, 0, stream>>>(x, actvh, idxm, Tg, Tb, W2h,
                                                meanp, rstdp, cgb, cbb, sgb, sbb,
                                                bgam, bbet, out);
}